// Round 4
// baseline (134.223 us; speedup 1.0000x reference)
//
#include <hip/hip_runtime.h>
#include <hip/hip_cooperative_groups.h>
#include <cstdint>

namespace cg = cooperative_groups;

// ---------------------------------------------------------------------------
// Exact-match index lookup via two hash tables (x-coord and y-coord).
// Reference semantics: idx = min row i where obs.x==qx OR obs.y==qy.
//   => idx = min( lookup_x(qx), lookup_y(qy) )
// Entry layout: one u64 per slot = (key_bits << 32) | min_index.
// EMPTY = 0xFFFFFFFFFFFFFFFF (key 0xFFFFFFFF is a NaN pattern; cannot occur).
// ---------------------------------------------------------------------------

#define LOG2_TABLE 18
#define TABLE_SIZE (1u << LOG2_TABLE)      // 262144 slots/table, load ~0.38
#define TABLE_MASK (TABLE_SIZE - 1u)
#define EMPTY64    0xFFFFFFFFFFFFFFFFull
#define NO_IDX     0xFFFFFFFFu

typedef unsigned long long u64;

__device__ __forceinline__ uint32_t hmix(uint32_t x) {
    x ^= x >> 16; x *= 0x7feb352du;
    x ^= x >> 15; x *= 0x846ca68bu;
    x ^= x >> 16;
    return x;
}

__device__ __forceinline__ void ht_insert(u64* __restrict__ tab,
                                          uint32_t kb, uint32_t idx) {
    u64 pack = ((u64)kb << 32) | (u64)idx;
    uint32_t h = hmix(kb) & TABLE_MASK;
    for (;;) {
        u64 cur = tab[h];
        if ((uint32_t)(cur >> 32) == kb) {
            // Key immutable once set; same high bits -> 64-bit min == idx min.
            atomicMin(&tab[h], pack);
            return;
        }
        if (cur == EMPTY64) {
            u64 old = atomicCAS(&tab[h], EMPTY64, pack);
            if (old == EMPTY64) return;
            if ((uint32_t)(old >> 32) == kb) { atomicMin(&tab[h], pack); return; }
            // slot stolen by a different key: keep probing
        }
        h = (h + 1u) & TABLE_MASK;
    }
}

__device__ __forceinline__ uint32_t ht_lookup(const u64* __restrict__ tab,
                                              uint32_t kb) {
    uint32_t h = hmix(kb) & TABLE_MASK;
    for (;;) {
        u64 cur = tab[h];
        if ((uint32_t)(cur >> 32) == kb) return (uint32_t)cur;
        if (cur == EMPTY64) return NO_IDX;
        h = (h + 1u) & TABLE_MASK;
    }
}

// ---------------------------------------------------------------------------
// Fused cooperative kernel: clear -> build -> probe+gather in ONE dispatch.
// 512 blocks x 256 threads (co-resident at 2 blocks/CU); grid.sync() between
// phases replaces two kernel launches (~10 us each of graph-node overhead).
// ---------------------------------------------------------------------------
__global__ __launch_bounds__(256)
void fused_kernel(const float2* __restrict__ qpos,
                  const float2* __restrict__ obs,
                  const float* __restrict__ zks,
                  float* __restrict__ out,
                  u64* __restrict__ ws,
                  int n_stars, int batch, int n_zk) {
    cg::grid_group grid = cg::this_grid();
    const int tid      = blockIdx.x * blockDim.x + threadIdx.x;
    const int nthreads = gridDim.x * blockDim.x;

    // ---- Phase 1: clear both tables (4 MiB) with 16B stores -------------
    ulonglong2* w2 = (ulonglong2*)ws;
    for (uint32_t t = tid; t < TABLE_SIZE; t += nthreads)     // 2*TS*8/16 = TS
        w2[t] = make_ulonglong2(EMPTY64, EMPTY64);

    grid.sync();

    // ---- Phase 2: insert all stars into both tables ---------------------
    u64* tx = ws;
    u64* ty = ws + TABLE_SIZE;
    for (int i = tid; i < n_stars; i += nthreads) {
        float2 s = obs[i];
        ht_insert(tx, __float_as_uint(s.x), (uint32_t)i);
        ht_insert(ty, __float_as_uint(s.y), (uint32_t)i);
    }

    grid.sync();

    // ---- Phase 3: probe + gather, one wave per query --------------------
    const int wid    = tid >> 6;
    const int lane   = tid & 63;
    const int nwaves = nthreads >> 6;
    for (int q = wid; q < batch; q += nwaves) {
        float2 Q = qpos[q];
        uint32_t ix = ht_lookup(tx, __float_as_uint(Q.x));
        uint32_t iy = ht_lookup(ty, __float_as_uint(Q.y));
        uint32_t idx = ix < iy ? ix : iy;
        if (idx == NO_IDX) idx = 0;   // all-false argmax -> 0 (can't happen)
        if (lane < n_zk)
            out[(long long)q * n_zk + lane] = zks[(long long)idx * n_zk + lane];
    }
}

// ---------------------------------------------------------------------------
// Non-cooperative 3-kernel fallback (if cooperative launch is unavailable).
// ---------------------------------------------------------------------------
__global__ void clear_kernel(ulonglong2* __restrict__ ws, int n16) {
    int t = blockIdx.x * blockDim.x + threadIdx.x;
    if (t < n16) ws[t] = make_ulonglong2(EMPTY64, EMPTY64);
}

__global__ void build_kernel(const float2* __restrict__ obs,
                             u64* __restrict__ ws, int n_stars) {
    int i = blockIdx.x * blockDim.x + threadIdx.x;
    if (i >= n_stars) return;
    float2 s = obs[i];
    ht_insert(ws, __float_as_uint(s.x), (uint32_t)i);
    ht_insert(ws + TABLE_SIZE, __float_as_uint(s.y), (uint32_t)i);
}

__global__ void probe_gather_kernel(const float2* __restrict__ qpos,
                                    const float* __restrict__ zks,
                                    const u64* __restrict__ ws,
                                    float* __restrict__ out,
                                    int batch, int n_zk) {
    int gid  = blockIdx.x * blockDim.x + threadIdx.x;
    int wid  = gid >> 6;
    int lane = gid & 63;
    if (wid >= batch) return;
    float2 q = qpos[wid];
    uint32_t ix = ht_lookup(ws, __float_as_uint(q.x));
    uint32_t iy = ht_lookup(ws + TABLE_SIZE, __float_as_uint(q.y));
    uint32_t idx = ix < iy ? ix : iy;
    if (idx == NO_IDX) idx = 0;
    if (lane < n_zk)
        out[(long long)wid * n_zk + lane] = zks[(long long)idx * n_zk + lane];
}

// ---------------------------------------------------------------------------
// Brute-force fallback (only if ws_size is too small for the tables).
// ---------------------------------------------------------------------------
#define SBLOCK 256
#define QCHUNK 512
#define SENTINEL 0x7fffffff

__global__ void init_idx(int* __restrict__ minidx, int batch) {
    int t = blockIdx.x * blockDim.x + threadIdx.x;
    if (t < batch) minidx[t] = SENTINEL;
}

__global__ __launch_bounds__(SBLOCK)
void scan_kernel(const float2* __restrict__ obs,
                 const float2* __restrict__ qpos,
                 int* __restrict__ minidx,
                 int n_stars, int batch) {
    __shared__ float2 q[QCHUNK];
    const int qbase = blockIdx.y * QCHUNK;
    for (int j = threadIdx.x; j < QCHUNK; j += SBLOCK) {
        int qi = qbase + j;
        if (qi < batch) q[j] = qpos[qi];
        else { float nv = __int_as_float(0x7fc00000); q[j] = make_float2(nv, nv); }
    }
    __syncthreads();
    const int i = blockIdx.x * SBLOCK + threadIdx.x;
    float sx, sy;
    if (i < n_stars) { float2 s = obs[i]; sx = s.x; sy = s.y; }
    else { sx = __int_as_float(0x7fc00000); sy = sx; }
    #pragma unroll 8
    for (int j = 0; j < QCHUNK; ++j) {
        float2 Q = q[j];
        if (sx == Q.x || sy == Q.y) atomicMin(&minidx[qbase + j], i);
    }
}

__global__ void gather_kernel(const float* __restrict__ zks,
                              const int* __restrict__ minidx,
                              float* __restrict__ out,
                              int batch, int n_zk) {
    int t = blockIdx.x * blockDim.x + threadIdx.x;
    int total = batch * n_zk;
    if (t >= total) return;
    int b = t / n_zk;
    int k = t - b * n_zk;
    int idx = minidx[b];
    if (idx == SENTINEL) idx = 0;
    out[t] = zks[(long long)idx * n_zk + k];
}

// ---------------------------------------------------------------------------
extern "C" void kernel_launch(void* const* d_in, const int* in_sizes, int n_in,
                              void* d_out, int out_size, void* d_ws, size_t ws_size,
                              hipStream_t stream) {
    const float2* qpos = (const float2*)d_in[0];   // positions (B, 2)
    const float2* obs  = (const float2*)d_in[1];   // obs_pos  (N, 2)
    const float*  zks  = (const float*)d_in[2];    // zks_prior (N, nz)

    int batch   = in_sizes[0] / 2;
    int n_stars = in_sizes[1] / 2;
    int n_zk    = in_sizes[2] / n_stars;

    float* out = (float*)d_out;

    const size_t table_bytes = (size_t)2 * TABLE_SIZE * sizeof(u64); // 4 MiB

    if (ws_size >= table_bytes) {
        u64* ws = (u64*)d_ws;

        void* args[] = { (void*)&qpos, (void*)&obs, (void*)&zks,
                         (void*)&out, (void*)&ws,
                         (void*)&n_stars, (void*)&batch, (void*)&n_zk };
        hipError_t err = hipLaunchCooperativeKernel(
            (const void*)fused_kernel, dim3(512), dim3(256), args, 0, stream);

        if (err != hipSuccess) {
            // Fallback: 3-dispatch pipeline.
            int n16 = (int)(table_bytes / 16);
            clear_kernel<<<(n16 + 255) / 256, 256, 0, stream>>>((ulonglong2*)ws, n16);
            build_kernel<<<(n_stars + 255) / 256, 256, 0, stream>>>(obs, ws, n_stars);
            int threads = batch * 64;
            probe_gather_kernel<<<(threads + 255) / 256, 256, 0, stream>>>(
                qpos, zks, ws, out, batch, n_zk);
        }
    } else {
        int* minidx = (int*)d_ws;
        init_idx<<<(batch + 255) / 256, 256, 0, stream>>>(minidx, batch);
        dim3 grid((n_stars + SBLOCK - 1) / SBLOCK, (batch + QCHUNK - 1) / QCHUNK);
        scan_kernel<<<grid, SBLOCK, 0, stream>>>(obs, qpos, minidx, n_stars, batch);
        int total = batch * n_zk;
        gather_kernel<<<(total + 255) / 256, 256, 0, stream>>>(zks, minidx, out,
                                                               batch, n_zk);
    }
}

// Round 5
// 39.039 us; speedup vs baseline: 3.4382x; 3.4382x over previous
//
#include <hip/hip_runtime.h>
#include <cstdint>

// ---------------------------------------------------------------------------
// Exact-match index lookup via two hash tables (x-coord and y-coord).
// Reference semantics: idx = min row i where obs.x==qx OR obs.y==qy.
//   => idx = min( lookup_x(qx), lookup_y(qy) )
// Entry layout: one u64 per slot = (key_bits << 32) | min_index.
// EMPTY = 0xFFFFFFFFFFFFFFFF (key 0xFFFFFFFF is a NaN pattern; cannot occur
// in finite random-normal data).
// Cooperative fusion tried in round 4: grid.sync() cost ~50us each -> reverted.
// ---------------------------------------------------------------------------

#define LOG2_TABLE 18
#define TABLE_SIZE (1u << LOG2_TABLE)      // 262144 slots/table, load ~0.38
#define TABLE_MASK (TABLE_SIZE - 1u)
#define EMPTY64    0xFFFFFFFFFFFFFFFFull
#define NO_IDX     0xFFFFFFFFu

typedef unsigned long long u64;

__device__ __forceinline__ uint32_t hmix(uint32_t x) {
    x ^= x >> 16; x *= 0x7feb352du;
    x ^= x >> 15; x *= 0x846ca68bu;
    x ^= x >> 16;
    return x;
}

__device__ __forceinline__ void ht_insert(u64* __restrict__ tab,
                                          uint32_t kb, uint32_t idx) {
    u64 pack = ((u64)kb << 32) | (u64)idx;
    uint32_t h = hmix(kb) & TABLE_MASK;
    for (;;) {
        u64 cur = tab[h];
        if ((uint32_t)(cur >> 32) == kb) {
            // Key immutable once set; same high bits -> 64-bit min == idx min.
            atomicMin(&tab[h], pack);
            return;
        }
        if (cur == EMPTY64) {
            u64 old = atomicCAS(&tab[h], EMPTY64, pack);
            if (old == EMPTY64) return;
            if ((uint32_t)(old >> 32) == kb) { atomicMin(&tab[h], pack); return; }
            // slot stolen by a different key: keep probing
        }
        h = (h + 1u) & TABLE_MASK;
    }
}

// ---------------------------------------------------------------------------
// Kernel 0: clear both tables (4 MiB) with 16B stores.
// 262144 stores / 256 = 1024 workgroups; ~1 us at HBM/L2 write rate.
// ---------------------------------------------------------------------------
__global__ __launch_bounds__(256)
void clear_kernel(ulonglong2* __restrict__ ws, int n16) {
    int t = blockIdx.x * blockDim.x + threadIdx.x;
    if (t < n16) ws[t] = make_ulonglong2(EMPTY64, EMPTY64);
}

// ---------------------------------------------------------------------------
// Kernel 1: insert all stars into both tables.
// ---------------------------------------------------------------------------
__global__ __launch_bounds__(256)
void build_kernel(const float2* __restrict__ obs,
                  u64* __restrict__ ws, int n_stars) {
    int i = blockIdx.x * blockDim.x + threadIdx.x;
    if (i >= n_stars) return;
    float2 s = obs[i];
    ht_insert(ws,              __float_as_uint(s.x), (uint32_t)i);
    ht_insert(ws + TABLE_SIZE, __float_as_uint(s.y), (uint32_t)i);
}

// ---------------------------------------------------------------------------
// Kernel 2: one wave per query; the two hash-chain walks (x-table, y-table)
// are hand-interleaved so their dependent loads overlap. All 64 lanes walk
// the same chain (same-address broadcast loads); lanes 0..n_zk-1 write out.
// ---------------------------------------------------------------------------
__global__ __launch_bounds__(256)
void probe_gather_kernel(const float2* __restrict__ qpos,
                         const float* __restrict__ zks,
                         const u64* __restrict__ ws,
                         float* __restrict__ out,
                         int batch, int n_zk) {
    int gid  = blockIdx.x * blockDim.x + threadIdx.x;
    int wid  = gid >> 6;
    int lane = gid & 63;
    if (wid >= batch) return;

    const u64* tx = ws;
    const u64* ty = ws + TABLE_SIZE;

    float2 q = qpos[wid];
    uint32_t kx = __float_as_uint(q.x);
    uint32_t ky = __float_as_uint(q.y);
    uint32_t hx = hmix(kx) & TABLE_MASK;
    uint32_t hy = hmix(ky) & TABLE_MASK;

    uint32_t ix = NO_IDX, iy = NO_IDX;
    bool dx = false, dy = false;
    while (!(dx && dy)) {
        u64 cx = dx ? 0 : tx[hx];       // both loads issue back-to-back:
        u64 cy = dy ? 0 : ty[hy];       // latencies overlap
        if (!dx) {
            if ((uint32_t)(cx >> 32) == kx) { ix = (uint32_t)cx; dx = true; }
            else if (cx == EMPTY64)         { dx = true; }
            else                            { hx = (hx + 1u) & TABLE_MASK; }
        }
        if (!dy) {
            if ((uint32_t)(cy >> 32) == ky) { iy = (uint32_t)cy; dy = true; }
            else if (cy == EMPTY64)         { dy = true; }
            else                            { hy = (hy + 1u) & TABLE_MASK; }
        }
    }

    uint32_t idx = ix < iy ? ix : iy;
    if (idx == NO_IDX) idx = 0;         // all-false argmax -> 0 (can't happen)

    if (lane < n_zk)
        out[(long long)wid * n_zk + lane] = zks[(long long)idx * n_zk + lane];
}

// ---------------------------------------------------------------------------
// Brute-force fallback (only if ws_size is too small for the tables).
// ---------------------------------------------------------------------------
#define SBLOCK 256
#define QCHUNK 512
#define SENTINEL 0x7fffffff

__global__ void init_idx(int* __restrict__ minidx, int batch) {
    int t = blockIdx.x * blockDim.x + threadIdx.x;
    if (t < batch) minidx[t] = SENTINEL;
}

__global__ __launch_bounds__(SBLOCK)
void scan_kernel(const float2* __restrict__ obs,
                 const float2* __restrict__ qpos,
                 int* __restrict__ minidx,
                 int n_stars, int batch) {
    __shared__ float2 q[QCHUNK];
    const int qbase = blockIdx.y * QCHUNK;
    for (int j = threadIdx.x; j < QCHUNK; j += SBLOCK) {
        int qi = qbase + j;
        if (qi < batch) q[j] = qpos[qi];
        else { float nv = __int_as_float(0x7fc00000); q[j] = make_float2(nv, nv); }
    }
    __syncthreads();
    const int i = blockIdx.x * SBLOCK + threadIdx.x;
    float sx, sy;
    if (i < n_stars) { float2 s = obs[i]; sx = s.x; sy = s.y; }
    else { sx = __int_as_float(0x7fc00000); sy = sx; }
    #pragma unroll 8
    for (int j = 0; j < QCHUNK; ++j) {
        float2 Q = q[j];
        if (sx == Q.x || sy == Q.y) atomicMin(&minidx[qbase + j], i);
    }
}

__global__ void gather_kernel(const float* __restrict__ zks,
                              const int* __restrict__ minidx,
                              float* __restrict__ out,
                              int batch, int n_zk) {
    int t = blockIdx.x * blockDim.x + threadIdx.x;
    int total = batch * n_zk;
    if (t >= total) return;
    int b = t / n_zk;
    int k = t - b * n_zk;
    int idx = minidx[b];
    if (idx == SENTINEL) idx = 0;
    out[t] = zks[(long long)idx * n_zk + k];
}

// ---------------------------------------------------------------------------
extern "C" void kernel_launch(void* const* d_in, const int* in_sizes, int n_in,
                              void* d_out, int out_size, void* d_ws, size_t ws_size,
                              hipStream_t stream) {
    const float2* qpos = (const float2*)d_in[0];   // positions (B, 2)
    const float2* obs  = (const float2*)d_in[1];   // obs_pos  (N, 2)
    const float*  zks  = (const float*)d_in[2];    // zks_prior (N, nz)

    int batch   = in_sizes[0] / 2;
    int n_stars = in_sizes[1] / 2;
    int n_zk    = in_sizes[2] / n_stars;

    float* out = (float*)d_out;

    const size_t table_bytes = (size_t)2 * TABLE_SIZE * sizeof(u64); // 4 MiB

    if (ws_size >= table_bytes) {
        u64* ws = (u64*)d_ws;
        int n16 = (int)(table_bytes / 16);           // 262144 x 16B stores
        clear_kernel<<<(n16 + 255) / 256, 256, 0, stream>>>((ulonglong2*)ws, n16);
        build_kernel<<<(n_stars + 255) / 256, 256, 0, stream>>>(obs, ws, n_stars);
        int threads = batch * 64;
        probe_gather_kernel<<<(threads + 255) / 256, 256, 0, stream>>>(
            qpos, zks, ws, out, batch, n_zk);
    } else {
        int* minidx = (int*)d_ws;
        init_idx<<<(batch + 255) / 256, 256, 0, stream>>>(minidx, batch);
        dim3 grid((n_stars + SBLOCK - 1) / SBLOCK, (batch + QCHUNK - 1) / QCHUNK);
        scan_kernel<<<grid, SBLOCK, 0, stream>>>(obs, qpos, minidx, n_stars, batch);
        int total = batch * n_zk;
        gather_kernel<<<(total + 255) / 256, 256, 0, stream>>>(zks, minidx, out,
                                                               batch, n_zk);
    }
}